// Round 1
// baseline (1882.893 us; speedup 1.0000x reference)
//
#include <hip/hip_runtime.h>
#include <hip/hip_bf16.h>
#include <math.h>

#define NTOK   8192      // B*S tokens
#define NEXP   64
#define EMBD   1024
#define MLPD   2048
#define TOPK   2
#define NFLAT  (NTOK * TOPK)

typedef __attribute__((ext_vector_type(4))) float  f32x4;
typedef __attribute__((ext_vector_type(8))) __bf16 bf16x8;

// ---------------- workspace layout (bytes) ----------------
#define OFF_COUNTS 0
#define OFF_BASE   256
#define OFF_RUN    512
#define OFF_EFLAT  1024
#define OFF_WFLAT  (1024 + 65536)
#define OFF_ROWTOK (1024 + 2 * 65536)
#define OFF_F2R    (1024 + 3 * 65536)
#define OFF_INTER  (1024 + 4 * 65536)                       // bf16 [16384][2048]
#define OFF_OS     (OFF_INTER + (size_t)NFLAT * MLPD * 2)   // out_sorted
#define NEED_F32   (OFF_OS + (size_t)NFLAT * EMBD * 4)
#define NEED_BF16  (OFF_OS + (size_t)NFLAT * EMBD * 2)

// ---------------- router: logits + top-2 + softmax ----------------
__global__ __launch_bounds__(256) void router_topk(
    const float* __restrict__ x, const float* __restrict__ gk,
    int* __restrict__ e_flat, float* __restrict__ w_flat) {
  int t = blockIdx.x * 4 + (threadIdx.x >> 6);
  int l = threadIdx.x & 63;
  const float* xr = x + (size_t)t * EMBD;
  float acc = 0.f;
  #pragma unroll 8
  for (int i = 0; i < EMBD; ++i)
    acc = fmaf(xr[i], gk[i * NEXP + l], acc);
  // max with lowest-index tiebreak (matches lax.top_k)
  float m = acc;
  for (int o = 32; o; o >>= 1) m = fmaxf(m, __shfl_xor(m, o));
  unsigned long long b1 = __ballot(acc == m);
  int i1 = __ffsll(b1) - 1;
  float v2 = (l == i1) ? -INFINITY : acc;
  float m2 = v2;
  for (int o = 32; o; o >>= 1) m2 = fmaxf(m2, __shfl_xor(m2, o));
  unsigned long long b2 = __ballot(v2 == m2);
  int i2 = __ffsll(b2) - 1;
  if (l == 0) {
    float e2 = expf(m2 - m);
    float inv = 1.f / (1.f + e2);
    e_flat[2 * t] = i1;  e_flat[2 * t + 1] = i2;
    w_flat[2 * t] = inv; w_flat[2 * t + 1] = e2 * inv;
  }
}

// ---------------- histogram / scan / scatter ----------------
__global__ void hist_k(const int* __restrict__ ef, int* __restrict__ counts) {
  int j = blockIdx.x * 256 + threadIdx.x;
  if (j < NFLAT) atomicAdd(&counts[ef[j]], 1);
}

__global__ void scan_k(const int* __restrict__ counts, int* __restrict__ base) {
  if (threadIdx.x == 0) {
    int s = 0;
    for (int e = 0; e < NEXP; ++e) { base[e] = s; s += counts[e]; }
  }
}

// within-expert order from atomics is arbitrary; final combine is
// permutation-invariant (each sorted row's value depends only on (token,expert))
__global__ void scatter_k(const int* __restrict__ ef, const int* __restrict__ base,
                          int* __restrict__ run, int* __restrict__ rowtok,
                          int* __restrict__ f2r) {
  int j = blockIdx.x * 256 + threadIdx.x;
  if (j < NFLAT) {
    int e = ef[j];
    int r = base[e] + atomicAdd(&run[e], 1);
    f2r[j] = r;
    rowtok[r] = j >> 1;
  }
}

// ---------------- grouped GEMM 1: inter = silu(x@w0) * (x@w1) ----------------
// grid (16 n-tiles, 64 experts), 256 thr = 4 waves in 2x2, wave tile 64x64,
// register-direct operands (no LDS): A = gathered x rows (k-contiguous 16B
// loads), B = w0/w1 columns via 8 strided scalar f32 loads + cvt.
__global__ __launch_bounds__(256, 2) void gemm1_k(
    const float* __restrict__ x, const float* __restrict__ w0,
    const float* __restrict__ w1, const int* __restrict__ counts,
    const int* __restrict__ base, const int* __restrict__ rowtok,
    __hip_bfloat16* __restrict__ inter) {
  int e = blockIdx.y;
  int Me = counts[e];
  if (Me == 0) return;
  int rs = base[e];
  int nt = blockIdx.x;
  int wv = threadIdx.x >> 6, l = threadIdx.x & 63;
  int wr = wv >> 1, wc = wv & 1;
  int lg = l >> 4, li = l & 15;
  int n_base = nt * 128 + wc * 64;
  const size_t we_off = (size_t)e * EMBD * MLPD;
  int nchunks = (Me + 127) >> 7;

  for (int mc = 0; mc < nchunks; ++mc) {
    int m0 = mc * 128 + wr * 64;
    int tok[4];
    #pragma unroll
    for (int mf = 0; mf < 4; ++mf) {
      int rl = m0 + mf * 16 + li;
      rl = rl < Me ? rl : Me - 1;
      tok[mf] = rowtok[rs + rl];
    }
    f32x4 acc0[4][4], acc1[4][4];
    #pragma unroll
    for (int i = 0; i < 4; ++i)
      #pragma unroll
      for (int j = 0; j < 4; ++j) {
        acc0[i][j] = (f32x4){0.f, 0.f, 0.f, 0.f};
        acc1[i][j] = (f32x4){0.f, 0.f, 0.f, 0.f};
      }

    for (int kk = 0; kk < EMBD; kk += 32) {
      bf16x8 a[4];
      #pragma unroll
      for (int mf = 0; mf < 4; ++mf) {
        const f32x4* ap = (const f32x4*)(x + (size_t)tok[mf] * EMBD + kk + lg * 8);
        f32x4 f0 = ap[0], f1 = ap[1];
        bf16x8 tv;
        #pragma unroll
        for (int q = 0; q < 4; ++q) { tv[q] = (__bf16)f0[q]; tv[4 + q] = (__bf16)f1[q]; }
        a[mf] = tv;
      }
      #pragma unroll
      for (int nf = 0; nf < 4; ++nf) {
        int n = n_base + nf * 16 + li;
        const float* p0 = w0 + we_off + (size_t)(kk + lg * 8) * MLPD + n;
        const float* p1 = w1 + we_off + (size_t)(kk + lg * 8) * MLPD + n;
        bf16x8 b0, b1;
        #pragma unroll
        for (int q = 0; q < 8; ++q) {
          b0[q] = (__bf16)p0[(size_t)q * MLPD];
          b1[q] = (__bf16)p1[(size_t)q * MLPD];
        }
        #pragma unroll
        for (int mf = 0; mf < 4; ++mf) {
          acc0[mf][nf] = __builtin_amdgcn_mfma_f32_16x16x32_bf16(a[mf], b0, acc0[mf][nf], 0, 0, 0);
          acc1[mf][nf] = __builtin_amdgcn_mfma_f32_16x16x32_bf16(a[mf], b1, acc1[mf][nf], 0, 0, 0);
        }
      }
    }
    // epilogue: silu(h0)*h1 -> bf16 inter
    #pragma unroll
    for (int mf = 0; mf < 4; ++mf)
      #pragma unroll
      for (int i = 0; i < 4; ++i) {
        int rl = m0 + mf * 16 + lg * 4 + i;
        if (rl < Me) {
          size_t rowoff = (size_t)(rs + rl) * MLPD;
          #pragma unroll
          for (int nf = 0; nf < 4; ++nf) {
            float h0 = acc0[mf][nf][i], h1 = acc1[mf][nf][i];
            float s = h0 / (1.f + expf(-h0)) * h1;
            inter[rowoff + n_base + nf * 16 + li] = (__hip_bfloat16)s;
          }
        }
      }
  }
}

// ---------------- grouped GEMM 2: out_sorted = inter @ wo ----------------
template <typename OS_T>
__global__ __launch_bounds__(256, 2) void gemm2_k(
    const __hip_bfloat16* __restrict__ inter, const float* __restrict__ wo,
    const int* __restrict__ counts, const int* __restrict__ base,
    OS_T* __restrict__ os) {
  int e = blockIdx.y;
  int Me = counts[e];
  if (Me == 0) return;
  int rs = base[e];
  int nt = blockIdx.x;
  int wv = threadIdx.x >> 6, l = threadIdx.x & 63;
  int wr = wv >> 1, wc = wv & 1;
  int lg = l >> 4, li = l & 15;
  int n_base = nt * 128 + wc * 64;
  const size_t we_off = (size_t)e * MLPD * EMBD;
  int nchunks = (Me + 127) >> 7;

  for (int mc = 0; mc < nchunks; ++mc) {
    int m0 = mc * 128 + wr * 64;
    int row[4];
    #pragma unroll
    for (int mf = 0; mf < 4; ++mf) {
      int rl = m0 + mf * 16 + li;
      rl = rl < Me ? rl : Me - 1;
      row[mf] = rs + rl;
    }
    f32x4 acc[4][4];
    #pragma unroll
    for (int i = 0; i < 4; ++i)
      #pragma unroll
      for (int j = 0; j < 4; ++j) acc[i][j] = (f32x4){0.f, 0.f, 0.f, 0.f};

    for (int kk = 0; kk < MLPD; kk += 32) {
      bf16x8 a[4];
      #pragma unroll
      for (int mf = 0; mf < 4; ++mf)
        a[mf] = *(const bf16x8*)(inter + (size_t)row[mf] * MLPD + kk + lg * 8);
      #pragma unroll
      for (int nf = 0; nf < 4; ++nf) {
        int n = n_base + nf * 16 + li;
        const float* p = wo + we_off + (size_t)(kk + lg * 8) * EMBD + n;
        bf16x8 b;
        #pragma unroll
        for (int q = 0; q < 8; ++q) b[q] = (__bf16)p[(size_t)q * EMBD];
        #pragma unroll
        for (int mf = 0; mf < 4; ++mf)
          acc[mf][nf] = __builtin_amdgcn_mfma_f32_16x16x32_bf16(a[mf], b, acc[mf][nf], 0, 0, 0);
      }
    }
    #pragma unroll
    for (int mf = 0; mf < 4; ++mf)
      #pragma unroll
      for (int i = 0; i < 4; ++i) {
        int rl = m0 + mf * 16 + lg * 4 + i;
        if (rl < Me) {
          size_t rowoff = (size_t)(rs + rl) * EMBD;
          #pragma unroll
          for (int nf = 0; nf < 4; ++nf)
            os[rowoff + n_base + nf * 16 + li] = (OS_T)acc[mf][nf][i];
        }
      }
  }
}

// ---------------- combine: out[t] = w1*os[r1] + w2*os[r2] ----------------
template <typename OS_T>
__global__ __launch_bounds__(256) void combine_k(
    const OS_T* __restrict__ os, const int* __restrict__ f2r,
    const float* __restrict__ wf, float* __restrict__ out) {
  int t = blockIdx.x;
  int c = threadIdx.x * 4;
  int r0 = f2r[2 * t], r1 = f2r[2 * t + 1];
  float wa = wf[2 * t], wb = wf[2 * t + 1];
  const OS_T* pa = os + (size_t)r0 * EMBD + c;
  const OS_T* pb = os + (size_t)r1 * EMBD + c;
  float4 o;
  o.x = wa * (float)pa[0] + wb * (float)pb[0];
  o.y = wa * (float)pa[1] + wb * (float)pb[1];
  o.z = wa * (float)pa[2] + wb * (float)pb[2];
  o.w = wa * (float)pa[3] + wb * (float)pb[3];
  *(float4*)(out + (size_t)t * EMBD + c) = o;
}

// ---------------- launcher ----------------
extern "C" void kernel_launch(void* const* d_in, const int* in_sizes, int n_in,
                              void* d_out, int out_size, void* d_ws, size_t ws_size,
                              hipStream_t stream) {
  const float* x  = (const float*)d_in[0];
  const float* gk = (const float*)d_in[1];
  const float* w0 = (const float*)d_in[2];
  const float* w1 = (const float*)d_in[3];
  const float* wo = (const float*)d_in[4];
  float* out = (float*)d_out;
  char* ws = (char*)d_ws;

  int*   counts = (int*)(ws + OFF_COUNTS);
  int*   basep  = (int*)(ws + OFF_BASE);
  int*   run    = (int*)(ws + OFF_RUN);
  int*   ef     = (int*)(ws + OFF_EFLAT);
  float* wfl    = (float*)(ws + OFF_WFLAT);
  int*   rowtok = (int*)(ws + OFF_ROWTOK);
  int*   f2r    = (int*)(ws + OFF_F2R);
  __hip_bfloat16* inter = (__hip_bfloat16*)(ws + OFF_INTER);

  hipMemsetAsync(ws, 0, 1024, stream);
  router_topk<<<NTOK / 4, 256, 0, stream>>>(x, gk, ef, wfl);
  hist_k<<<NFLAT / 256, 256, 0, stream>>>(ef, counts);
  scan_k<<<1, 64, 0, stream>>>(counts, basep);
  scatter_k<<<NFLAT / 256, 256, 0, stream>>>(ef, basep, run, rowtok, f2r);
  gemm1_k<<<dim3(16, 64), 256, 0, stream>>>(x, w0, w1, counts, basep, rowtok, inter);

  if (ws_size >= NEED_F32) {
    float* os = (float*)(ws + OFF_OS);
    gemm2_k<float><<<dim3(8, 64), 256, 0, stream>>>(inter, wo, counts, basep, os);
    combine_k<float><<<NTOK, 256, 0, stream>>>(os, f2r, wfl, out);
  } else {
    __hip_bfloat16* os = (__hip_bfloat16*)(ws + OFF_OS);
    gemm2_k<__hip_bfloat16><<<dim3(8, 64), 256, 0, stream>>>(inter, wo, counts, basep, os);
    combine_k<__hip_bfloat16><<<NTOK, 256, 0, stream>>>(os, f2r, wfl, out);
  }
}

// Round 2
// 1156.375 us; speedup vs baseline: 1.6283x; 1.6283x over previous
//
#include <hip/hip_runtime.h>
#include <hip/hip_bf16.h>
#include <math.h>

#define NTOK   8192      // B*S tokens
#define NEXP   64
#define EMBD   1024
#define MLPD   2048
#define TOPK   2
#define NFLAT  (NTOK * TOPK)
#define BKD    32        // K tile
#define BPAD   40        // padded LDS row stride for B tiles (bf16 elems), 80B = 5x16B
#define MAXCH  8         // max m-chunks of 128 per expert (binomial mean 256, 1024 is ~48 sigma)

typedef __attribute__((ext_vector_type(4))) float  f32x4;
typedef __attribute__((ext_vector_type(2))) float  f32x2;
typedef __attribute__((ext_vector_type(8))) __bf16 bf16x8;

// ---------------- workspace layout (bytes) ----------------
#define OFF_COUNTS 0
#define OFF_BASE   256
#define OFF_RUN    512
#define OFF_EFLAT  1024
#define OFF_WFLAT  (1024 + 65536)
#define OFF_ROWTOK (1024 + 2 * 65536)
#define OFF_F2R    (1024 + 3 * 65536)
#define OFF_INTER  (1024 + 4 * 65536)                       // bf16 [16384][2048]
#define OFF_OS     (OFF_INTER + (size_t)NFLAT * MLPD * 2)   // out_sorted
#define NEED_F32   (OFF_OS + (size_t)NFLAT * EMBD * 4)

// ---------------- router: logits + top-2 + softmax ----------------
__global__ __launch_bounds__(256) void router_topk(
    const float* __restrict__ x, const float* __restrict__ gk,
    int* __restrict__ e_flat, float* __restrict__ w_flat) {
  int t = blockIdx.x * 4 + (threadIdx.x >> 6);
  int l = threadIdx.x & 63;
  const float* xr = x + (size_t)t * EMBD;
  float acc = 0.f;
  #pragma unroll 8
  for (int i = 0; i < EMBD; ++i)
    acc = fmaf(xr[i], gk[i * NEXP + l], acc);
  float m = acc;
  for (int o = 32; o; o >>= 1) m = fmaxf(m, __shfl_xor(m, o));
  unsigned long long b1 = __ballot(acc == m);
  int i1 = __ffsll(b1) - 1;
  float v2 = (l == i1) ? -INFINITY : acc;
  float m2 = v2;
  for (int o = 32; o; o >>= 1) m2 = fmaxf(m2, __shfl_xor(m2, o));
  unsigned long long b2 = __ballot(v2 == m2);
  int i2 = __ffsll(b2) - 1;
  if (l == 0) {
    float e2 = expf(m2 - m);
    float inv = 1.f / (1.f + e2);
    e_flat[2 * t] = i1;  e_flat[2 * t + 1] = i2;
    w_flat[2 * t] = inv; w_flat[2 * t + 1] = e2 * inv;
  }
}

// ---------------- histogram / scan / scatter ----------------
__global__ void hist_k(const int* __restrict__ ef, int* __restrict__ counts) {
  int j = blockIdx.x * 256 + threadIdx.x;
  if (j < NFLAT) atomicAdd(&counts[ef[j]], 1);
}

__global__ void scan_k(const int* __restrict__ counts, int* __restrict__ base) {
  if (threadIdx.x == 0) {
    int s = 0;
    for (int e = 0; e < NEXP; ++e) { base[e] = s; s += counts[e]; }
  }
}

__global__ void scatter_k(const int* __restrict__ ef, const int* __restrict__ base,
                          int* __restrict__ run, int* __restrict__ rowtok,
                          int* __restrict__ f2r) {
  int j = blockIdx.x * 256 + threadIdx.x;
  if (j < NFLAT) {
    int e = ef[j];
    int r = base[e] + atomicAdd(&run[e], 1);
    f2r[j] = r;
    rowtok[r] = j >> 1;
  }
}

// ---------------- grouped GEMM 1: inter = silu(x@w0) * (x@w1) ----------------
// block tile 128(m) x 128(n) x 32(k), double-buffered LDS, reg-staged f32->bf16.
// 4 waves 2x2, wave tile 64x64. A LDS [128][32] linear; B LDS [128][40] padded,
// k-contiguous per column (transpose happens via per-thread k-strided f32x2 loads).
__global__ __launch_bounds__(256, 2) void gemm1_k(
    const float* __restrict__ x, const float* __restrict__ w0,
    const float* __restrict__ w1, const int* __restrict__ counts,
    const int* __restrict__ base, const int* __restrict__ rowtok,
    __hip_bfloat16* __restrict__ inter) {
  int e = blockIdx.z;
  int Me = counts[e];
  int mc = blockIdx.y;
  if (mc * 128 >= Me) return;
  int rs = base[e];
  int nb = blockIdx.x * 128;
  int t = threadIdx.x;
  int wv = t >> 6, l = t & 63;
  int wr = wv >> 1, wc = wv & 1;
  int lg = l >> 4, li = l & 15;

  __shared__ __bf16 Ash[2][128 * BKD];
  __shared__ __bf16 B0sh[2][128 * BPAD];
  __shared__ __bf16 B1sh[2][128 * BPAD];

  // staging map: A -> thread (ra = t>>1 row, kh = t&1 k-half of 16 floats)
  int ra = t >> 1, kh = t & 1;
  int rga = mc * 128 + ra; rga = rga < Me ? rga : Me - 1;
  const float* asrc = x + (size_t)rowtok[rs + rga] * EMBD + kh * 16;
  // staging map: B -> thread (n2 = t&63 col pair, kg = t>>6 k-octet)
  int n2 = t & 63, kg = t >> 6;
  const size_t weoff = (size_t)e * EMBD * MLPD;
  const float* b0src = w0 + weoff + (size_t)(kg * 8) * MLPD + nb + n2 * 2;
  const float* b1src = w1 + weoff + (size_t)(kg * 8) * MLPD + nb + n2 * 2;

  f32x4 va[4];
  f32x2 vb0[8], vb1[8];

  auto LOAD = [&](int kk) {
    #pragma unroll
    for (int j = 0; j < 4; ++j)
      va[j] = *(const f32x4*)(asrc + kk + j * 4);
    #pragma unroll
    for (int q = 0; q < 8; ++q) {
      vb0[q] = *(const f32x2*)(b0src + (size_t)(kk + q) * MLPD);
      vb1[q] = *(const f32x2*)(b1src + (size_t)(kk + q) * MLPD);
    }
  };
  auto CVTW = [&](int c) {
    bf16x8 a0, a1;
    #pragma unroll
    for (int i = 0; i < 4; ++i) {
      a0[i] = (__bf16)va[0][i]; a0[4 + i] = (__bf16)va[1][i];
      a1[i] = (__bf16)va[2][i]; a1[4 + i] = (__bf16)va[3][i];
    }
    *(bf16x8*)(&Ash[c][ra * BKD + kh * 16])     = a0;
    *(bf16x8*)(&Ash[c][ra * BKD + kh * 16 + 8]) = a1;
    bf16x8 c0, c1, d0, d1;
    #pragma unroll
    for (int q = 0; q < 8; ++q) {
      c0[q] = (__bf16)vb0[q][0]; c1[q] = (__bf16)vb0[q][1];
      d0[q] = (__bf16)vb1[q][0]; d1[q] = (__bf16)vb1[q][1];
    }
    *(bf16x8*)(&B0sh[c][(n2 * 2)     * BPAD + kg * 8]) = c0;
    *(bf16x8*)(&B0sh[c][(n2 * 2 + 1) * BPAD + kg * 8]) = c1;
    *(bf16x8*)(&B1sh[c][(n2 * 2)     * BPAD + kg * 8]) = d0;
    *(bf16x8*)(&B1sh[c][(n2 * 2 + 1) * BPAD + kg * 8]) = d1;
  };

  f32x4 acc0[4][4], acc1[4][4];
  #pragma unroll
  for (int i = 0; i < 4; ++i)
    #pragma unroll
    for (int j = 0; j < 4; ++j) {
      acc0[i][j] = (f32x4){0.f, 0.f, 0.f, 0.f};
      acc1[i][j] = (f32x4){0.f, 0.f, 0.f, 0.f};
    }

  LOAD(0);
  CVTW(0);
  int c = 0;
  const int NT = EMBD / BKD;  // 32
  for (int ks = 0; ks < NT; ++ks) {
    __syncthreads();
    if (ks + 1 < NT) LOAD((ks + 1) * BKD);   // issue next-tile loads; overlap MFMA
    bf16x8 af[4], bf0[4], bf1[4];
    #pragma unroll
    for (int mf = 0; mf < 4; ++mf)
      af[mf] = *(const bf16x8*)(&Ash[c][(wr * 64 + mf * 16 + li) * BKD + lg * 8]);
    #pragma unroll
    for (int nf = 0; nf < 4; ++nf) {
      bf0[nf] = *(const bf16x8*)(&B0sh[c][(wc * 64 + nf * 16 + li) * BPAD + lg * 8]);
      bf1[nf] = *(const bf16x8*)(&B1sh[c][(wc * 64 + nf * 16 + li) * BPAD + lg * 8]);
    }
    #pragma unroll
    for (int nf = 0; nf < 4; ++nf)
      #pragma unroll
      for (int mf = 0; mf < 4; ++mf) {
        acc0[mf][nf] = __builtin_amdgcn_mfma_f32_16x16x32_bf16(af[mf], bf0[nf], acc0[mf][nf], 0, 0, 0);
        acc1[mf][nf] = __builtin_amdgcn_mfma_f32_16x16x32_bf16(af[mf], bf1[nf], acc1[mf][nf], 0, 0, 0);
      }
    if (ks + 1 < NT) { CVTW(c ^ 1); c ^= 1; }
  }

  // epilogue: silu(h0)*h1 -> bf16 inter
  #pragma unroll
  for (int mf = 0; mf < 4; ++mf)
    #pragma unroll
    for (int i = 0; i < 4; ++i) {
      int rl = mc * 128 + wr * 64 + mf * 16 + lg * 4 + i;
      if (rl < Me) {
        size_t rowoff = (size_t)(rs + rl) * MLPD;
        #pragma unroll
        for (int nf = 0; nf < 4; ++nf) {
          float h0 = acc0[mf][nf][i], h1 = acc1[mf][nf][i];
          float s = h0 / (1.f + expf(-h0)) * h1;
          inter[rowoff + nb + wc * 64 + nf * 16 + li] = (__hip_bfloat16)s;
        }
      }
    }
}

// ---------------- grouped GEMM 2: out_sorted = inter @ wo ----------------
template <typename OS_T>
__global__ __launch_bounds__(256, 2) void gemm2_k(
    const __hip_bfloat16* __restrict__ inter, const float* __restrict__ wo,
    const int* __restrict__ counts, const int* __restrict__ base,
    OS_T* __restrict__ os) {
  int e = blockIdx.z;
  int Me = counts[e];
  int mc = blockIdx.y;
  if (mc * 128 >= Me) return;
  int rs = base[e];
  int nb = blockIdx.x * 128;
  int t = threadIdx.x;
  int wv = t >> 6, l = t & 63;
  int wr = wv >> 1, wc = wv & 1;
  int lg = l >> 4, li = l & 15;

  __shared__ __bf16 Ash[2][128 * BKD];
  __shared__ __bf16 Bsh[2][128 * BPAD];

  int ra = t >> 1, kh = t & 1;
  int rga = mc * 128 + ra; rga = rga < Me ? rga : Me - 1;
  const __hip_bfloat16* asrc = inter + (size_t)(rs + rga) * MLPD + kh * 16;
  int n2 = t & 63, kg = t >> 6;
  const size_t weoff = (size_t)e * MLPD * EMBD;
  const float* bsrc = wo + weoff + (size_t)(kg * 8) * EMBD + nb + n2 * 2;

  bf16x8 va[2];
  f32x2 vb[8];

  auto LOAD = [&](int kk) {
    va[0] = *(const bf16x8*)(asrc + kk);
    va[1] = *(const bf16x8*)(asrc + kk + 8);
    #pragma unroll
    for (int q = 0; q < 8; ++q)
      vb[q] = *(const f32x2*)(bsrc + (size_t)(kk + q) * EMBD);
  };
  auto CVTW = [&](int c) {
    *(bf16x8*)(&Ash[c][ra * BKD + kh * 16])     = va[0];
    *(bf16x8*)(&Ash[c][ra * BKD + kh * 16 + 8]) = va[1];
    bf16x8 c0, c1;
    #pragma unroll
    for (int q = 0; q < 8; ++q) {
      c0[q] = (__bf16)vb[q][0]; c1[q] = (__bf16)vb[q][1];
    }
    *(bf16x8*)(&Bsh[c][(n2 * 2)     * BPAD + kg * 8]) = c0;
    *(bf16x8*)(&Bsh[c][(n2 * 2 + 1) * BPAD + kg * 8]) = c1;
  };

  f32x4 acc[4][4];
  #pragma unroll
  for (int i = 0; i < 4; ++i)
    #pragma unroll
    for (int j = 0; j < 4; ++j) acc[i][j] = (f32x4){0.f, 0.f, 0.f, 0.f};

  LOAD(0);
  CVTW(0);
  int c = 0;
  const int NT = MLPD / BKD;  // 64
  for (int ks = 0; ks < NT; ++ks) {
    __syncthreads();
    if (ks + 1 < NT) LOAD((ks + 1) * BKD);
    bf16x8 af[4], bfr[4];
    #pragma unroll
    for (int mf = 0; mf < 4; ++mf)
      af[mf] = *(const bf16x8*)(&Ash[c][(wr * 64 + mf * 16 + li) * BKD + lg * 8]);
    #pragma unroll
    for (int nf = 0; nf < 4; ++nf)
      bfr[nf] = *(const bf16x8*)(&Bsh[c][(wc * 64 + nf * 16 + li) * BPAD + lg * 8]);
    #pragma unroll
    for (int nf = 0; nf < 4; ++nf)
      #pragma unroll
      for (int mf = 0; mf < 4; ++mf)
        acc[mf][nf] = __builtin_amdgcn_mfma_f32_16x16x32_bf16(af[mf], bfr[nf], acc[mf][nf], 0, 0, 0);
    if (ks + 1 < NT) { CVTW(c ^ 1); c ^= 1; }
  }

  #pragma unroll
  for (int mf = 0; mf < 4; ++mf)
    #pragma unroll
    for (int i = 0; i < 4; ++i) {
      int rl = mc * 128 + wr * 64 + mf * 16 + lg * 4 + i;
      if (rl < Me) {
        size_t rowoff = (size_t)(rs + rl) * EMBD;
        #pragma unroll
        for (int nf = 0; nf < 4; ++nf)
          os[rowoff + nb + wc * 64 + nf * 16 + li] = (OS_T)acc[mf][nf][i];
      }
    }
}

// ---------------- combine: out[t] = w1*os[r1] + w2*os[r2] ----------------
template <typename OS_T>
__global__ __launch_bounds__(256) void combine_k(
    const OS_T* __restrict__ os, const int* __restrict__ f2r,
    const float* __restrict__ wf, float* __restrict__ out) {
  int t = blockIdx.x;
  int c = threadIdx.x * 4;
  int r0 = f2r[2 * t], r1 = f2r[2 * t + 1];
  float wa = wf[2 * t], wb = wf[2 * t + 1];
  const OS_T* pa = os + (size_t)r0 * EMBD + c;
  const OS_T* pb = os + (size_t)r1 * EMBD + c;
  float4 o;
  o.x = wa * (float)pa[0] + wb * (float)pb[0];
  o.y = wa * (float)pa[1] + wb * (float)pb[1];
  o.z = wa * (float)pa[2] + wb * (float)pb[2];
  o.w = wa * (float)pa[3] + wb * (float)pb[3];
  *(float4*)(out + (size_t)t * EMBD + c) = o;
}

// ---------------- launcher ----------------
extern "C" void kernel_launch(void* const* d_in, const int* in_sizes, int n_in,
                              void* d_out, int out_size, void* d_ws, size_t ws_size,
                              hipStream_t stream) {
  const float* x  = (const float*)d_in[0];
  const float* gk = (const float*)d_in[1];
  const float* w0 = (const float*)d_in[2];
  const float* w1 = (const float*)d_in[3];
  const float* wo = (const float*)d_in[4];
  float* out = (float*)d_out;
  char* ws = (char*)d_ws;

  int*   counts = (int*)(ws + OFF_COUNTS);
  int*   basep  = (int*)(ws + OFF_BASE);
  int*   run    = (int*)(ws + OFF_RUN);
  int*   ef     = (int*)(ws + OFF_EFLAT);
  float* wfl    = (float*)(ws + OFF_WFLAT);
  int*   rowtok = (int*)(ws + OFF_ROWTOK);
  int*   f2r    = (int*)(ws + OFF_F2R);
  __hip_bfloat16* inter = (__hip_bfloat16*)(ws + OFF_INTER);

  hipMemsetAsync(ws, 0, 1024, stream);
  router_topk<<<NTOK / 4, 256, 0, stream>>>(x, gk, ef, wfl);
  hist_k<<<NFLAT / 256, 256, 0, stream>>>(ef, counts);
  scan_k<<<1, 64, 0, stream>>>(counts, basep);
  scatter_k<<<NFLAT / 256, 256, 0, stream>>>(ef, basep, run, rowtok, f2r);
  gemm1_k<<<dim3(16, MAXCH, 64), 256, 0, stream>>>(x, w0, w1, counts, basep, rowtok, inter);

  if (ws_size >= NEED_F32) {
    float* os = (float*)(ws + OFF_OS);
    gemm2_k<float><<<dim3(8, MAXCH, 64), 256, 0, stream>>>(inter, wo, counts, basep, os);
    combine_k<float><<<NTOK, 256, 0, stream>>>(os, f2r, wfl, out);
  } else {
    __hip_bfloat16* os = (__hip_bfloat16*)(ws + OFF_OS);
    gemm2_k<__hip_bfloat16><<<dim3(8, MAXCH, 64), 256, 0, stream>>>(inter, wo, counts, basep, os);
    combine_k<__hip_bfloat16><<<NTOK, 256, 0, stream>>>(os, f2r, wfl, out);
  }
}